// Round 3
// baseline (432.927 us; speedup 1.0000x reference)
//
#include <hip/hip_runtime.h>

#define N_NODES 100000
#define N_EDGES 1600000
#define C 128
#define LEAKY 0.01f
#define BN_EPS 1e-5f
#define NB1 391            // ceil(N_NODES/256)

typedef __attribute__((ext_vector_type(8))) short short8;   // 8 bf16 = 16B (4 VGPRs)
typedef __attribute__((ext_vector_type(4))) float f32x4;

__device__ __forceinline__ unsigned short f2bf(float f) {   // RNE float->bf16
    unsigned int u = __builtin_bit_cast(unsigned int, f);
    u += 0x7FFFu + ((u >> 16) & 1u);
    return (unsigned short)(u >> 16);
}
__device__ __forceinline__ float bf2f(unsigned short b) {
    unsigned int u = ((unsigned int)b) << 16;
    return __builtin_bit_cast(float, u);
}

// ---------------------------------------------------------------- init
__global__ __launch_bounds__(256) void k_init(int* __restrict__ cnt,
                                              int* __restrict__ cursor,
                                              float* __restrict__ sums,
                                              float* __restrict__ sumsq) {
    int i = blockIdx.x * 256 + threadIdx.x;
    if (i < N_NODES) { cnt[i] = 0; cursor[i] = 0; }
    if (i < C) { sums[i] = 0.0f; sumsq[i] = 0.0f; }
}

// ---------------------------------------------------------------- in-degree count
__global__ __launch_bounds__(256) void k_count(const int* __restrict__ dst,
                                               int* __restrict__ cnt) {
    int e = blockIdx.x * 256 + threadIdx.x;
    if (e < N_EDGES) atomicAdd(&cnt[dst[e]], 1);
}

// ---------------------------------------------------------------- dinv = rsqrt(deg+1)
__global__ __launch_bounds__(256) void k_dinv(const int* __restrict__ cnt,
                                              float* __restrict__ dinv) {
    int i = blockIdx.x * 256 + threadIdx.x;
    if (i < N_NODES) dinv[i] = rsqrtf((float)(cnt[i] + 1));
}

// ---------------------------------------------------------------- 3-pass exclusive scan
__global__ __launch_bounds__(256) void k_scan1(const int* __restrict__ cnt,
                                               int* __restrict__ offs,
                                               int* __restrict__ bsum) {
    __shared__ int tmp[256];
    int i = blockIdx.x * 256 + threadIdx.x;
    int v = (i < N_NODES) ? cnt[i] : 0;
    tmp[threadIdx.x] = v;
    __syncthreads();
    for (int off = 1; off < 256; off <<= 1) {
        int t = (threadIdx.x >= off) ? tmp[threadIdx.x - off] : 0;
        __syncthreads();
        tmp[threadIdx.x] += t;
        __syncthreads();
    }
    if (i < N_NODES) offs[i] = tmp[threadIdx.x] - v;
    if (threadIdx.x == 255) bsum[blockIdx.x] = tmp[255];
}

__global__ __launch_bounds__(512) void k_scan2(int* __restrict__ bsum) {
    __shared__ int tmp[512];
    int v = (threadIdx.x < NB1) ? bsum[threadIdx.x] : 0;
    tmp[threadIdx.x] = v;
    __syncthreads();
    for (int off = 1; off < 512; off <<= 1) {
        int t = (threadIdx.x >= off) ? tmp[threadIdx.x - off] : 0;
        __syncthreads();
        tmp[threadIdx.x] += t;
        __syncthreads();
    }
    if (threadIdx.x < NB1) bsum[threadIdx.x] = tmp[threadIdx.x] - v;
}

__global__ __launch_bounds__(256) void k_scan3(int* __restrict__ offs,
                                               const int* __restrict__ bsum) {
    int i = blockIdx.x * 256 + threadIdx.x;
    if (i < N_NODES) offs[i] += bsum[blockIdx.x];
}

// ---------------------------------------------------------------- bucket fill
__global__ __launch_bounds__(256) void k_fill(const int* __restrict__ src,
                                              const int* __restrict__ dst,
                                              const int* __restrict__ offs,
                                              int* __restrict__ cursor,
                                              int* __restrict__ srt) {
    int e = blockIdx.x * 256 + threadIdx.x;
    int d = dst[e];
    int pos = offs[d] + atomicAdd(&cursor[d], 1);
    srt[pos] = src[e];
}

// ---------------------------------------------------------------- cast x -> bf16 (vectorized)
__global__ __launch_bounds__(256) void k_castx(const float* __restrict__ x,
                                               unsigned short* __restrict__ xb) {
    int i = blockIdx.x * 256 + threadIdx.x;  // float4 index, N*C/4 total
    float4 v = ((const float4*)x)[i];
    ushort4 o;
    o.x = f2bf(v.x); o.y = f2bf(v.y); o.z = f2bf(v.z); o.w = f2bf(v.w);
    ((ushort4*)xb)[i] = o;
}

// ---------------------------------------------------------------- cast+transpose W -> Wt bf16 [c][k]
__global__ __launch_bounds__(256) void k_castw(const float* __restrict__ W,
                                               unsigned short* __restrict__ wt) {
    int i = blockIdx.x * 256 + threadIdx.x;  // i = c*128 + k
    int c = i >> 7, k = i & 127;
    wt[i] = f2bf(W[k * C + c]);
}

// ---------------------------------------------------------------- h = x @ W via MFMA bf16, one wave per 16-row tile
__global__ __launch_bounds__(256) void k_gemm(const unsigned short* __restrict__ xb,
                                              const unsigned short* __restrict__ wt,
                                              unsigned short* __restrict__ hb) {
    int tile = blockIdx.x * 4 + (threadIdx.x >> 6);
    if (tile >= N_NODES / 16) return;
    int lane = threadIdx.x & 63;
    int row0 = tile * 16;

    int ar = lane & 15;              // A row within tile
    int kg = (lane >> 4) * 8;        // k-subgroup base

    // A fragments: 4 k-steps of 32
    short8 a[4];
    #pragma unroll
    for (int kk = 0; kk < 4; ++kk)
        a[kk] = *(const short8*)&xb[(size_t)(row0 + ar) * C + kk * 32 + kg];

    #pragma unroll
    for (int ct = 0; ct < 8; ++ct) {
        f32x4 acc = {0.f, 0.f, 0.f, 0.f};
        #pragma unroll
        for (int kk = 0; kk < 4; ++kk) {
            short8 b = *(const short8*)&wt[(size_t)(ct * 16 + ar) * C + kk * 32 + kg];
            acc = __builtin_amdgcn_mfma_f32_16x16x32_bf16(a[kk], b, acc, 0, 0, 0);
        }
        // C/D: col = lane&15, row = (lane>>4)*4 + r
        int col = ct * 16 + ar;
        int rb = (lane >> 4) * 4;
        #pragma unroll
        for (int r = 0; r < 4; ++r)
            hb[(size_t)(row0 + rb + r) * C + col] = f2bf(acc[r]);
    }
}

// ---------------------------------------------------------------- CSR aggregate (bf16 h), 32 lanes per node
__global__ __launch_bounds__(256) void k_aggregate(const unsigned short* __restrict__ hb,
                                                   const int* __restrict__ srt,
                                                   const int* __restrict__ offs,
                                                   const int* __restrict__ cnt,
                                                   const float* __restrict__ dinv,
                                                   const float* __restrict__ bias,
                                                   float* __restrict__ out) {
    int node = blockIdx.x * 8 + (threadIdx.x >> 5);
    int lane = threadIdx.x & 31;
    const ushort4* h4 = (const ushort4*)hb;   // 8B per lane = 4 channels

    float dn = dinv[node];
    float sl = dn * dn;
    ushort4 hv = h4[(size_t)node * 32 + lane];
    float4 acc = make_float4(bf2f(hv.x) * sl, bf2f(hv.y) * sl,
                             bf2f(hv.z) * sl, bf2f(hv.w) * sl);

    int beg = offs[node];
    int end = beg + cnt[node];
    for (int k = beg; k < end; ++k) {
        int s = srt[k];
        float nm = dn * dinv[s];
        ushort4 m = h4[(size_t)s * 32 + lane];
        acc.x += nm * bf2f(m.x);
        acc.y += nm * bf2f(m.y);
        acc.z += nm * bf2f(m.z);
        acc.w += nm * bf2f(m.w);
    }

    float4 b = ((const float4*)bias)[lane];
    acc.x += b.x; acc.y += b.y; acc.z += b.z; acc.w += b.w;
    acc.x = acc.x > 0.f ? acc.x : LEAKY * acc.x;
    acc.y = acc.y > 0.f ? acc.y : LEAKY * acc.y;
    acc.z = acc.z > 0.f ? acc.z : LEAKY * acc.z;
    acc.w = acc.w > 0.f ? acc.w : LEAKY * acc.w;
    ((float4*)out)[(size_t)node * 32 + lane] = acc;
}

// ---------------------------------------------------------------- BN stats
__global__ __launch_bounds__(256) void k_stats(const float* __restrict__ out,
                                               float* __restrict__ sums,
                                               float* __restrict__ sumsq) {
    int c = threadIdx.x & 127;
    int half = threadIdx.x >> 7;
    int base = blockIdx.x * 256;
    float s = 0.0f, q = 0.0f;
    for (int r = half; r < 256; r += 2) {
        int n = base + r;
        if (n >= N_NODES) break;
        float v = out[(size_t)n * C + c];
        s += v; q += v * v;
    }
    __shared__ float ls[256], lq[256];
    ls[threadIdx.x] = s; lq[threadIdx.x] = q;
    __syncthreads();
    if (threadIdx.x < 128) {
        atomicAdd(&sums[c],  ls[threadIdx.x] + ls[threadIdx.x + 128]);
        atomicAdd(&sumsq[c], lq[threadIdx.x] + lq[threadIdx.x + 128]);
    }
}

// ---------------------------------------------------------------- fold BN params
__global__ void k_params(const float* __restrict__ sums, const float* __restrict__ sumsq,
                         const float* __restrict__ gamma, const float* __restrict__ beta,
                         float* __restrict__ scale, float* __restrict__ shift) {
    int c = threadIdx.x;
    float inv_n = 1.0f / (float)N_NODES;
    float mean = sums[c] * inv_n;
    float var = sumsq[c] * inv_n - mean * mean;
    float sc = gamma[c] * rsqrtf(var + BN_EPS);
    scale[c] = sc;
    shift[c] = beta[c] - mean * sc;
}

// ---------------------------------------------------------------- apply
__global__ __launch_bounds__(256) void k_apply(float* __restrict__ out,
                                               const float* __restrict__ scale,
                                               const float* __restrict__ shift) {
    int i = blockIdx.x * 256 + threadIdx.x;
    int c4 = i & 31;
    float4 v = ((float4*)out)[i];
    float4 sc = ((const float4*)scale)[c4];
    float4 sh = ((const float4*)shift)[c4];
    v.x = v.x * sc.x + sh.x;
    v.y = v.y * sc.y + sh.y;
    v.z = v.z * sc.z + sh.z;
    v.w = v.w * sc.w + sh.w;
    ((float4*)out)[i] = v;
}

extern "C" void kernel_launch(void* const* d_in, const int* in_sizes, int n_in,
                              void* d_out, int out_size, void* d_ws, size_t ws_size,
                              hipStream_t stream) {
    const float* x     = (const float*)d_in[0];
    const int*   edge  = (const int*)d_in[1];
    const float* W     = (const float*)d_in[2];
    const float* bias  = (const float*)d_in[3];
    const float* gamma = (const float*)d_in[4];
    const float* beta  = (const float*)d_in[5];
    float* out = (float*)d_out;
    char* ws = (char*)d_ws;

    // workspace layout (~59 MB)
    unsigned short* xb  = (unsigned short*)ws;  ws += (size_t)N_NODES * C * 2;  // 25.6 MB
    unsigned short* hb  = (unsigned short*)ws;  ws += (size_t)N_NODES * C * 2;  // 25.6 MB
    unsigned short* wt  = (unsigned short*)ws;  ws += (size_t)C * C * 2;        // 32 KB
    int*   srt    = (int*)ws;                   ws += (size_t)N_EDGES * 4;      // 6.4 MB
    int*   cnt    = (int*)ws;                   ws += (size_t)N_NODES * 4;
    int*   offs   = (int*)ws;                   ws += (size_t)N_NODES * 4;
    int*   cursor = (int*)ws;                   ws += (size_t)N_NODES * 4;
    int*   bsum   = (int*)ws;                   ws += 512 * 4;
    float* dinv   = (float*)ws;                 ws += (size_t)N_NODES * 4;
    float* sums   = (float*)ws;                 ws += C * 4;
    float* sumsq  = (float*)ws;                 ws += C * 4;
    float* scale  = (float*)ws;                 ws += C * 4;
    float* shift  = (float*)ws;

    const int* src = edge;
    const int* dst = edge + N_EDGES;

    k_init     <<<NB1,                  256, 0, stream>>>(cnt, cursor, sums, sumsq);
    k_count    <<<N_EDGES / 256,        256, 0, stream>>>(dst, cnt);
    k_dinv     <<<NB1,                  256, 0, stream>>>(cnt, dinv);
    k_scan1    <<<NB1,                  256, 0, stream>>>(cnt, offs, bsum);
    k_scan2    <<<1,                    512, 0, stream>>>(bsum);
    k_scan3    <<<NB1,                  256, 0, stream>>>(offs, bsum);
    k_fill     <<<N_EDGES / 256,        256, 0, stream>>>(src, dst, offs, cursor, srt);
    k_castx    <<<N_NODES * C / 4 / 256, 256, 0, stream>>>(x, xb);
    k_castw    <<<C * C / 256,          256, 0, stream>>>(W, wt);
    k_gemm     <<<(N_NODES / 16 + 3) / 4, 256, 0, stream>>>(xb, wt, hb);
    k_aggregate<<<N_NODES / 8,          256, 0, stream>>>(hb, srt, offs, cnt, dinv, bias, out);
    k_stats    <<<NB1,                  256, 0, stream>>>(out, sums, sumsq);
    k_params   <<<1, 128,                    0, stream>>>(sums, sumsq, gamma, beta, scale, shift);
    k_apply    <<<N_NODES * C / 4 / 256, 256, 0, stream>>>(out, scale, shift);
}

// Round 4
// 339.703 us; speedup vs baseline: 1.2744x; 1.2744x over previous
//
#include <hip/hip_runtime.h>

#define N_NODES 100000
#define N_EDGES 1600000
#define C 128
#define LEAKY 0.01f
#define BN_EPS 1e-5f
#define NB1 391            // ceil(N_NODES/256)

typedef __attribute__((ext_vector_type(8))) short short8;   // 8 bf16 = 16B
typedef __attribute__((ext_vector_type(4))) float f32x4;

__device__ __forceinline__ unsigned short f2bf(float f) {   // RNE float->bf16
    unsigned int u = __builtin_bit_cast(unsigned int, f);
    u += 0x7FFFu + ((u >> 16) & 1u);
    return (unsigned short)(u >> 16);
}
__device__ __forceinline__ float bf2f(unsigned short b) {
    unsigned int u = ((unsigned int)b) << 16;
    return __builtin_bit_cast(float, u);
}

// ---------------------------------------------------------------- init: zero cnt/cursor/stats + cast-transpose W
__global__ __launch_bounds__(256) void k_init(int* __restrict__ cnt,
                                              int* __restrict__ cursor,
                                              float* __restrict__ sums,
                                              float* __restrict__ sumsq,
                                              const float* __restrict__ W,
                                              unsigned short* __restrict__ wt) {
    int i = blockIdx.x * 256 + threadIdx.x;
    if (i < N_NODES) { cnt[i] = 0; cursor[i] = 0; }
    if (i < C) { sums[i] = 0.0f; sumsq[i] = 0.0f; }
    if (i < C * C) wt[i] = f2bf(W[(i & 127) * C + (i >> 7)]);   // wt[c][k] = W[k][c]
}

// ---------------------------------------------------------------- in-degree count
__global__ __launch_bounds__(256) void k_count(const int* __restrict__ dst,
                                               int* __restrict__ cnt) {
    int e = blockIdx.x * 256 + threadIdx.x;
    if (e < N_EDGES) atomicAdd(&cnt[dst[e]], 1);
}

// ---------------------------------------------------------------- scan pass 1 (+ dinv = rsqrt(deg+1))
__global__ __launch_bounds__(256) void k_scan1(const int* __restrict__ cnt,
                                               int* __restrict__ offs,
                                               int* __restrict__ bsum,
                                               float* __restrict__ dinv) {
    __shared__ int tmp[256];
    int i = blockIdx.x * 256 + threadIdx.x;
    int v = (i < N_NODES) ? cnt[i] : 0;
    if (i < N_NODES) dinv[i] = rsqrtf((float)(v + 1));
    tmp[threadIdx.x] = v;
    __syncthreads();
    for (int off = 1; off < 256; off <<= 1) {
        int t = (threadIdx.x >= off) ? tmp[threadIdx.x - off] : 0;
        __syncthreads();
        tmp[threadIdx.x] += t;
        __syncthreads();
    }
    if (i < N_NODES) offs[i] = tmp[threadIdx.x] - v;
    if (threadIdx.x == 255) bsum[blockIdx.x] = tmp[255];
}

// ---------------------------------------------------------------- scan pass 2
__global__ __launch_bounds__(512) void k_scan2(int* __restrict__ bsum) {
    __shared__ int tmp[512];
    int v = (threadIdx.x < NB1) ? bsum[threadIdx.x] : 0;
    tmp[threadIdx.x] = v;
    __syncthreads();
    for (int off = 1; off < 512; off <<= 1) {
        int t = (threadIdx.x >= off) ? tmp[threadIdx.x - off] : 0;
        __syncthreads();
        tmp[threadIdx.x] += t;
        __syncthreads();
    }
    if (threadIdx.x < NB1) bsum[threadIdx.x] = tmp[threadIdx.x] - v;
}

// ---------------------------------------------------------------- scan pass 3 (+ sentinel offs[N] = E)
__global__ __launch_bounds__(256) void k_scan3(int* __restrict__ offs,
                                               const int* __restrict__ bsum) {
    int i = blockIdx.x * 256 + threadIdx.x;
    if (i < N_NODES) offs[i] += bsum[blockIdx.x];
    if (i == 0) offs[N_NODES] = N_EDGES;
}

// ---------------------------------------------------------------- bucket fill
__global__ __launch_bounds__(256) void k_fill(const int* __restrict__ src,
                                              const int* __restrict__ dst,
                                              const int* __restrict__ offs,
                                              int* __restrict__ cursor,
                                              int* __restrict__ srt) {
    int e = blockIdx.x * 256 + threadIdx.x;
    int d = dst[e];
    int pos = offs[d] + atomicAdd(&cursor[d], 1);
    srt[pos] = src[e];
}

// ---------------------------------------------------------------- hs = (x @ W) * dinv[row], bf16, fused f32->bf16 cast
__global__ __launch_bounds__(256) void k_gemm(const float* __restrict__ x,
                                              const unsigned short* __restrict__ wt,
                                              const float* __restrict__ dinv,
                                              unsigned short* __restrict__ hs) {
    int tile = blockIdx.x * 4 + (threadIdx.x >> 6);
    if (tile >= N_NODES / 16) return;
    int lane = threadIdx.x & 63;
    int row0 = tile * 16;

    int ar = lane & 15;              // A row within tile / B col row
    int kg = (lane >> 4) * 8;        // k-subgroup base

    // A fragments from f32 x, converted in-register
    short8 a[4];
    #pragma unroll
    for (int kk = 0; kk < 4; ++kk) {
        const float* p = &x[(size_t)(row0 + ar) * C + kk * 32 + kg];
        float4 p0 = *(const float4*)p;
        float4 p1 = *(const float4*)(p + 4);
        short8 av;
        av[0] = (short)f2bf(p0.x); av[1] = (short)f2bf(p0.y);
        av[2] = (short)f2bf(p0.z); av[3] = (short)f2bf(p0.w);
        av[4] = (short)f2bf(p1.x); av[5] = (short)f2bf(p1.y);
        av[6] = (short)f2bf(p1.z); av[7] = (short)f2bf(p1.w);
        a[kk] = av;
    }

    int rb = (lane >> 4) * 4;
    float dv[4];
    #pragma unroll
    for (int r = 0; r < 4; ++r) dv[r] = dinv[row0 + rb + r];

    #pragma unroll
    for (int ct = 0; ct < 8; ++ct) {
        f32x4 acc = {0.f, 0.f, 0.f, 0.f};
        #pragma unroll
        for (int kk = 0; kk < 4; ++kk) {
            short8 b = *(const short8*)&wt[(size_t)(ct * 16 + ar) * C + kk * 32 + kg];
            acc = __builtin_amdgcn_mfma_f32_16x16x32_bf16(a[kk], b, acc, 0, 0, 0);
        }
        int col = ct * 16 + ar;      // C/D: col=lane&15, row=(lane>>4)*4+r
        #pragma unroll
        for (int r = 0; r < 4; ++r)
            hs[(size_t)(row0 + rb + r) * C + col] = f2bf(acc[r] * dv[r]);
    }
}

// ---------------------------------------------------------------- CSR aggregate: 32 lanes/node, 8-wide MLP gathers
// out[d] = leaky( dn * (hs[d] + sum_bucket hs[s]) + bias )
__global__ __launch_bounds__(256) void k_aggregate(const ushort4* __restrict__ h4,
                                                   const int* __restrict__ srt,
                                                   const int* __restrict__ offs,
                                                   const float* __restrict__ dinv,
                                                   const float* __restrict__ bias,
                                                   float* __restrict__ out) {
    int node = blockIdx.x * 8 + (threadIdx.x >> 5);
    int lane = threadIdx.x & 31;

    float dn = dinv[node];
    int beg = offs[node];
    int end = offs[node + 1];

    ushort4 ms = h4[(size_t)node * 32 + lane];
    float ax = bf2f(ms.x), ay = bf2f(ms.y), az = bf2f(ms.z), aw = bf2f(ms.w);

    for (int k = beg; k < end; k += 8) {
        int   idx[8];
        float msk[8];
        #pragma unroll
        for (int i = 0; i < 8; ++i) {
            int ki = k + i;
            msk[i] = (ki < end) ? 1.0f : 0.0f;
            idx[i] = srt[(ki < end) ? ki : end - 1];
        }
        ushort4 m[8];
        #pragma unroll
        for (int i = 0; i < 8; ++i) m[i] = h4[(size_t)idx[i] * 32 + lane];
        #pragma unroll
        for (int i = 0; i < 8; ++i) {
            ax += msk[i] * bf2f(m[i].x);
            ay += msk[i] * bf2f(m[i].y);
            az += msk[i] * bf2f(m[i].z);
            aw += msk[i] * bf2f(m[i].w);
        }
    }

    float4 b = ((const float4*)bias)[lane];
    float4 v;
    v.x = dn * ax + b.x;
    v.y = dn * ay + b.y;
    v.z = dn * az + b.z;
    v.w = dn * aw + b.w;
    v.x = v.x > 0.f ? v.x : LEAKY * v.x;
    v.y = v.y > 0.f ? v.y : LEAKY * v.y;
    v.z = v.z > 0.f ? v.z : LEAKY * v.z;
    v.w = v.w > 0.f ? v.w : LEAKY * v.w;
    ((float4*)out)[(size_t)node * 32 + lane] = v;
}

// ---------------------------------------------------------------- BN stats
__global__ __launch_bounds__(256) void k_stats(const float* __restrict__ out,
                                               float* __restrict__ sums,
                                               float* __restrict__ sumsq) {
    int c = threadIdx.x & 127;
    int half = threadIdx.x >> 7;
    int base = blockIdx.x * 256;
    float s = 0.0f, q = 0.0f;
    for (int r = half; r < 256; r += 2) {
        int n = base + r;
        if (n >= N_NODES) break;
        float v = out[(size_t)n * C + c];
        s += v; q += v * v;
    }
    __shared__ float ls[256], lq[256];
    ls[threadIdx.x] = s; lq[threadIdx.x] = q;
    __syncthreads();
    if (threadIdx.x < 128) {
        atomicAdd(&sums[c],  ls[threadIdx.x] + ls[threadIdx.x + 128]);
        atomicAdd(&sumsq[c], lq[threadIdx.x] + lq[threadIdx.x + 128]);
    }
}

// ---------------------------------------------------------------- fold BN params
__global__ void k_params(const float* __restrict__ sums, const float* __restrict__ sumsq,
                         const float* __restrict__ gamma, const float* __restrict__ beta,
                         float* __restrict__ scale, float* __restrict__ shift) {
    int c = threadIdx.x;
    float inv_n = 1.0f / (float)N_NODES;
    float mean = sums[c] * inv_n;
    float var = sumsq[c] * inv_n - mean * mean;
    float sc = gamma[c] * rsqrtf(var + BN_EPS);
    scale[c] = sc;
    shift[c] = beta[c] - mean * sc;
}

// ---------------------------------------------------------------- apply
__global__ __launch_bounds__(256) void k_apply(float* __restrict__ out,
                                               const float* __restrict__ scale,
                                               const float* __restrict__ shift) {
    int i = blockIdx.x * 256 + threadIdx.x;
    int c4 = i & 31;
    float4 v = ((float4*)out)[i];
    float4 sc = ((const float4*)scale)[c4];
    float4 sh = ((const float4*)shift)[c4];
    v.x = v.x * sc.x + sh.x;
    v.y = v.y * sc.y + sh.y;
    v.z = v.z * sc.z + sh.z;
    v.w = v.w * sc.w + sh.w;
    ((float4*)out)[i] = v;
}

extern "C" void kernel_launch(void* const* d_in, const int* in_sizes, int n_in,
                              void* d_out, int out_size, void* d_ws, size_t ws_size,
                              hipStream_t stream) {
    const float* x     = (const float*)d_in[0];
    const int*   edge  = (const int*)d_in[1];
    const float* W     = (const float*)d_in[2];
    const float* bias  = (const float*)d_in[3];
    const float* gamma = (const float*)d_in[4];
    const float* beta  = (const float*)d_in[5];
    float* out = (float*)d_out;
    char* ws = (char*)d_ws;

    // workspace layout (~34 MB)
    unsigned short* hs  = (unsigned short*)ws;  ws += (size_t)N_NODES * C * 2;  // 25.6 MB
    unsigned short* wt  = (unsigned short*)ws;  ws += (size_t)C * C * 2;        // 32 KB
    int*   srt    = (int*)ws;                   ws += (size_t)N_EDGES * 4;      // 6.4 MB
    int*   cnt    = (int*)ws;                   ws += (size_t)N_NODES * 4;
    int*   offs   = (int*)ws;                   ws += (size_t)(N_NODES + 1) * 4;
    int*   cursor = (int*)ws;                   ws += (size_t)N_NODES * 4;
    int*   bsum   = (int*)ws;                   ws += 512 * 4;
    float* dinv   = (float*)ws;                 ws += (size_t)N_NODES * 4;
    float* sums   = (float*)ws;                 ws += C * 4;
    float* sumsq  = (float*)ws;                 ws += C * 4;
    float* scale  = (float*)ws;                 ws += C * 4;
    float* shift  = (float*)ws;

    const int* src = edge;
    const int* dst = edge + N_EDGES;

    k_init     <<<NB1,                   256, 0, stream>>>(cnt, cursor, sums, sumsq, W, wt);
    k_count    <<<N_EDGES / 256,         256, 0, stream>>>(dst, cnt);
    k_scan1    <<<NB1,                   256, 0, stream>>>(cnt, offs, bsum, dinv);
    k_scan2    <<<1,                     512, 0, stream>>>(bsum);
    k_scan3    <<<NB1,                   256, 0, stream>>>(offs, bsum);
    k_fill     <<<N_EDGES / 256,         256, 0, stream>>>(src, dst, offs, cursor, srt);
    k_gemm     <<<(N_NODES / 16 + 3) / 4, 256, 0, stream>>>(x, wt, dinv, hs);
    k_aggregate<<<N_NODES / 8,           256, 0, stream>>>((const ushort4*)hs, srt, offs, dinv, bias, out);
    k_stats    <<<NB1,                   256, 0, stream>>>(out, sums, sumsq);
    k_params   <<<1, 128,                     0, stream>>>(sums, sumsq, gamma, beta, scale, shift);
    k_apply    <<<N_NODES * C / 4 / 256, 256, 0, stream>>>(out, scale, shift);
}